// Round 2
// baseline (280.490 us; speedup 1.0000x reference)
//
#include <hip/hip_runtime.h>

// TTLinear fused: out = x @ (core0 @ core1)^T + bias, rank-8 structure.
// One kernel. Each block owns 8 tokens end-to-end:
//   Phase A: y[t][r] = sum_i x[t][i]*core1[r][i]   (y in LDS, 512 B)
//   Phase B: out[t][o] = bias[o] + sum_r y[t][r]*core0[o][r]
// HBM traffic: 128 MB x read + 128 MB out write (structural minimum).
// core0/core1 (128 KB each) are L2/L3-resident re-reads per block.

#define TOKENS 8192
#define IN_F   4096
#define OUT_F  4096
#define RANK   8

__global__ __launch_bounds__(256) void tt_fused(const float* __restrict__ x,
                                                const float* __restrict__ core0,
                                                const float* __restrict__ core1,
                                                const float* __restrict__ bias,
                                                float* __restrict__ out) {
    __shared__ float y_s[8][RANK];   // 8 tokens x rank-8, 256 B

    const int tid  = threadIdx.x;
    const int wave = tid >> 6;
    const int lane = tid & 63;
    const int t0   = blockIdx.x * 8;

    // ---- Phase A: wave w computes y for tokens t0+2w, t0+2w+1 ----
    const float* x0 = x + (size_t)(t0 + wave * 2) * IN_F;
    const float* x1 = x0 + IN_F;

    float acc0[RANK], acc1[RANK];
    #pragma unroll
    for (int r = 0; r < RANK; ++r) { acc0[r] = 0.f; acc1[r] = 0.f; }

    #pragma unroll 4
    for (int k = 0; k < 16; ++k) {
        const int i = 4 * (lane + 64 * k);      // coalesced float4 chunks
        const float4 a0 = *(const float4*)(x0 + i);
        const float4 a1 = *(const float4*)(x1 + i);
        #pragma unroll
        for (int r = 0; r < RANK; ++r) {
            const float4 c = *(const float4*)(core1 + r * IN_F + i);
            acc0[r] += a0.x * c.x + a0.y * c.y + a0.z * c.z + a0.w * c.w;
            acc1[r] += a1.x * c.x + a1.y * c.y + a1.z * c.z + a1.w * c.w;
        }
    }

    // butterfly reduce across the 64-lane wave
    #pragma unroll
    for (int r = 0; r < RANK; ++r) {
        #pragma unroll
        for (int off = 32; off > 0; off >>= 1) {
            acc0[r] += __shfl_xor(acc0[r], off, 64);
            acc1[r] += __shfl_xor(acc1[r], off, 64);
        }
    }

    if (lane == 0) {
        #pragma unroll
        for (int r = 0; r < RANK; ++r) {
            y_s[wave * 2][r]     = acc0[r];
            y_s[wave * 2 + 1][r] = acc1[r];
        }
    }
    __syncthreads();

    // ---- Phase B: expand 8 tokens x 4096 outputs, coalesced float4 stores.
    // Thread handles o = j*1024 + tid*4 for j = 0..3; core0[4][8]+bias in
    // registers per j-chunk; y broadcast from LDS.
    #pragma unroll
    for (int j = 0; j < 4; ++j) {
        const int o = j * 1024 + tid * 4;

        float4 w[8];
        #pragma unroll
        for (int q = 0; q < 4; ++q) {
            w[2 * q]     = *(const float4*)(core0 + (o + q) * RANK);
            w[2 * q + 1] = *(const float4*)(core0 + (o + q) * RANK + 4);
        }
        const float4 b = *(const float4*)(bias + o);

        #pragma unroll
        for (int t = 0; t < 8; ++t) {
            const float4 y0 = *(const float4*)(&y_s[t][0]);
            const float4 y1 = *(const float4*)(&y_s[t][4]);
            float4 c;
            c.x = b.x + y0.x * w[0].x + y0.y * w[0].y + y0.z * w[0].z + y0.w * w[0].w
                      + y1.x * w[1].x + y1.y * w[1].y + y1.z * w[1].z + y1.w * w[1].w;
            c.y = b.y + y0.x * w[2].x + y0.y * w[2].y + y0.z * w[2].z + y0.w * w[2].w
                      + y1.x * w[3].x + y1.y * w[3].y + y1.z * w[3].z + y1.w * w[3].w;
            c.z = b.z + y0.x * w[4].x + y0.y * w[4].y + y0.z * w[4].z + y0.w * w[4].w
                      + y1.x * w[5].x + y1.y * w[5].y + y1.z * w[5].z + y1.w * w[5].w;
            c.w = b.w + y0.x * w[6].x + y0.y * w[6].y + y0.z * w[6].z + y0.w * w[6].w
                      + y1.x * w[7].x + y1.y * w[7].y + y1.z * w[7].z + y1.w * w[7].w;
            *(float4*)(out + (size_t)(t0 + t) * OUT_F + o) = c;
        }
    }
}

extern "C" void kernel_launch(void* const* d_in, const int* in_sizes, int n_in,
                              void* d_out, int out_size, void* d_ws, size_t ws_size,
                              hipStream_t stream) {
    const float* x     = (const float*)d_in[0];  // [8192, 4096]
    const float* core0 = (const float*)d_in[1];  // [1, 4096, 8] -> [o][r]
    const float* core1 = (const float*)d_in[2];  // [8, 4096, 1] -> [r][i]
    const float* bias  = (const float*)d_in[3];  // [4096]
    float* out = (float*)d_out;                  // [8192, 4096]

    tt_fused<<<TOKENS / 8, 256, 0, stream>>>(x, core0, core1, bias, out);
}